// Round 9
// baseline (315.052 us; speedup 1.0000x reference)
//
#include <hip/hip_runtime.h>

#define T256 256
#define SB 1024
#define BIG 1024
#define RANGE_D 25000   // deg f32 bins/pass: 100 KB LDS, 2 passes
#define RANGE_B 25000   // bucket cursors/pass: 100 KB LDS, 2 passes
#define HALF_N 25000    // packed u16 count bins: (N+1)/2 u32 = 100 KB, 1 pass
#define ITEMS 8         // scan1: 8192 elements per block (bsum index = g>>13)

// ================= atomic-free path =================

// single pass: packed-u16 count histogram of col over ALL N bins (chunk <= 65535)
__global__ void __launch_bounds__(BIG)
histc_kernel(const int* __restrict__ col, int* __restrict__ H, int E, int N, int chunk) {
  __shared__ unsigned sc32[HALF_N];
  int b = blockIdx.x;
  long base = (long)b * chunk;
  int cnt = (int)min((long)chunk, (long)E - base);
  if (cnt < 0) cnt = 0;
  int t = threadIdx.x;
  int half = (N + 1) >> 1;
  for (int i = t; i < half; i += BIG) sc32[i] = 0u;
  __syncthreads();
  for (int i = t; i < cnt; i += BIG) {
    int c = col[base + i];
    atomicAdd(&sc32[c >> 1], 1u << ((c & 1) << 4));   // LDS atomic, packed u16
  }
  __syncthreads();
  for (int i = t; i < N; i += BIG)
    H[(long)b * N + i] = (int)((sc32[i >> 1] >> ((i & 1) << 4)) & 0xFFFFu);
}

// 2 range-passes: f32 weighted histogram of row
__global__ void __launch_bounds__(BIG)
histd_kernel(const int* __restrict__ row, const float* __restrict__ w,
             float* __restrict__ degH, int E, int N, int chunk) {
  __shared__ float sd[RANGE_D];
  int b = blockIdx.x;
  int lo = blockIdx.y * RANGE_D;
  int hi = min(lo + RANGE_D, N);
  int len = hi - lo;
  long base = (long)b * chunk;
  int cnt = (int)min((long)chunk, (long)E - base);
  if (cnt < 0) cnt = 0;
  int t = threadIdx.x;
  for (int i = t; i < len; i += BIG) sd[i] = 0.f;
  __syncthreads();
  for (int i = t; i < cnt; i += BIG) {
    long e = base + i;
    int r = row[e];
    if (r >= lo && r < hi) atomicAdd(&sd[r - lo], w[e]);   // LDS atomic
  }
  __syncthreads();
  for (int i = t; i < len; i += BIG) degH[(long)b * N + lo + i] = sd[i];
}

// thread-per-bin: exclusive column prefix of H over blocks (coalesced), totals -> cnt,
// fused degH column-reduce -> disq
__global__ void colscan_kernel(int* __restrict__ H, const float* __restrict__ degH,
                               float* __restrict__ disq, int* __restrict__ cnt,
                               int N, int nB) {
  int c = blockIdx.x * blockDim.x + threadIdx.x;
  if (c >= N) return;
  int s = 0;
  float d = 0.f;
  for (int b = 0; b < nB; b++) {
    long idx = (long)b * N + c;
    int h = H[idx];
    H[idx] = s;       // exclusive prefix within column
    s += h;
    d += degH[idx];
  }
  cnt[c] = s;
  disq[c] = (d > 0.f) ? rsqrtf(d) : 0.f;
}

// scan stage 1 over contiguous array (8192 elems/block)
__global__ void __launch_bounds__(SB)
scan1_kernel(int* __restrict__ a, int* __restrict__ bsum, int n) {
  __shared__ int s[SB];
  int t = threadIdx.x;
  int g0 = blockIdx.x * (SB * ITEMS) + t * ITEMS;
  int v[ITEMS];
  int tot = 0;
#pragma unroll
  for (int k = 0; k < ITEMS; k++) {
    int g = g0 + k;
    int u = (g < n) ? a[g] : 0;
    v[k] = u; tot += u;
  }
  s[t] = tot;
  __syncthreads();
  for (int d = 1; d < SB; d <<= 1) {
    int u = (t >= d) ? s[t - d] : 0;
    __syncthreads();
    s[t] += u;
    __syncthreads();
  }
  int run = s[t] - tot;
#pragma unroll
  for (int k = 0; k < ITEMS; k++) {
    int g = g0 + k;
    if (g < n) a[g] = run;
    run += v[k];
  }
  if (t == SB - 1) bsum[blockIdx.x] = s[SB - 1];
}

__global__ void __launch_bounds__(SB)
scan_top_kernel(int* __restrict__ bsum, int nb) {
  __shared__ int s[SB];
  int t = threadIdx.x;
  int v = (t < nb) ? bsum[t] : 0;
  s[t] = v;
  __syncthreads();
  for (int d = 1; d < SB; d <<= 1) {
    int u = (t >= d) ? s[t - d] : 0;
    __syncthreads();
    s[t] += u;
    __syncthreads();
  }
  if (t < nb) bsum[t] = s[t] - v;
}

__global__ void scan_add_kernel(int* __restrict__ a, const int* __restrict__ bsum, int n) {
  int g = blockIdx.x * blockDim.x + threadIdx.x;
  if (g < n) a[g] += bsum[g >> 13];
}

// grid (nB, nRB): block (b,p) places chunk b's edges with col in range p.
// cursor base = starts[c] + H[b][c]; LDS atomics only.
__global__ void __launch_bounds__(BIG)
bucket2_kernel(const int* __restrict__ row, const int* __restrict__ col,
               const float* __restrict__ w, const float* __restrict__ disq,
               const int* __restrict__ H, const int* __restrict__ starts,
               int2* __restrict__ pairs, int E, int N, int chunk) {
  __shared__ int cur[RANGE_B];
  int b = blockIdx.x;
  int lo = blockIdx.y * RANGE_B;
  int hi = min(lo + RANGE_B, N);
  int len = hi - lo;
  long base = (long)b * chunk;
  int cnt = (int)min((long)chunk, (long)E - base);
  if (cnt < 0) cnt = 0;
  int t = threadIdx.x;
  for (int i = t; i < len; i += BIG)
    cur[i] = H[(long)b * N + lo + i] + starts[lo + i];
  __syncthreads();
  for (int i = t; i < cnt; i += BIG) {
    long e = base + i;
    int c = col[e];
    if (c >= lo && c < hi) {
      int r = row[e];
      float nm = -w[e] * disq[r] * disq[c];
      int pos = atomicAdd(&cur[c - lo], 1);   // LDS atomic, exclusive (b,c) ranges
      pairs[pos] = make_int2(r, __float_as_int(nm));
    }
  }
}

// ================= legacy fallback (device atomics) =================

__global__ void zero_kernel(int* __restrict__ p, long n) {
  long i = (long)blockIdx.x * blockDim.x + threadIdx.x;
  long stride = (long)gridDim.x * blockDim.x;
  for (; i < n; i += stride) p[i] = 0;
}

__global__ void deghist_dev_kernel(const float* __restrict__ w, const int* __restrict__ row,
                                   const int* __restrict__ col, float* __restrict__ deg,
                                   int* __restrict__ cntArr, int E) {
  int e = blockIdx.x * blockDim.x + threadIdx.x;
  if (e < E) {
    atomicAdd(&deg[row[e]], w[e]);
    atomicAdd(&cntArr[col[e]], 1);
  }
}

__global__ void bucket_dev_kernel(const float* __restrict__ w, const int* __restrict__ row,
                                  const int* __restrict__ col, const float* __restrict__ disq,
                                  int* __restrict__ off, int2* __restrict__ pairs, int E) {
  int e = blockIdx.x * blockDim.x + threadIdx.x;
  if (e >= E) return;
  int r = row[e], c = col[e];
  float v = -w[e] * disq[r] * disq[c];
  int p = atomicAdd(&off[c], 1);
  pairs[p] = make_int2(r, __float_as_int(v));
}

// ================= shared tail =================

// MODE 0: S[c] = start, end = S[c+1] (or E).  MODE 1: S[c] = end, start = S[c-1] (or 0).
template <int MODE>
__global__ void gather_kernel(const float* __restrict__ x, const int* __restrict__ S,
                              const int2* __restrict__ pairs, float* __restrict__ Tx,
                              int n, int E) {
  int wid = (int)(((long)blockIdx.x * blockDim.x + threadIdx.x) >> 6);
  if (wid >= n) return;
  int lane = threadIdx.x & 63;
  int slot = lane >> 3;
  int f4 = lane & 7;
  int start, end;
  if (MODE == 0) { start = S[wid]; end = (wid + 1 < n) ? S[wid + 1] : E; }
  else           { start = wid ? S[wid - 1] : 0; end = S[wid]; }
  float4 acc = make_float4(0.f, 0.f, 0.f, 0.f);
  int i = start + slot;
  // 2-deep unroll: 16 edges in flight per wave
  for (; i + 8 < end; i += 16) {
    int2 p0 = pairs[i];
    int2 p1 = pairs[i + 8];
    float4 x0 = *(const float4*)(x + (long)p0.x * 32 + f4 * 4);
    float4 x1 = *(const float4*)(x + (long)p1.x * 32 + f4 * 4);
    float v0 = __int_as_float(p0.y);
    float v1 = __int_as_float(p1.y);
    acc.x += v0 * x0.x; acc.y += v0 * x0.y; acc.z += v0 * x0.z; acc.w += v0 * x0.w;
    acc.x += v1 * x1.x; acc.y += v1 * x1.y; acc.z += v1 * x1.z; acc.w += v1 * x1.w;
  }
  if (i < end) {
    int2 p0 = pairs[i];
    float4 x0 = *(const float4*)(x + (long)p0.x * 32 + f4 * 4);
    float v0 = __int_as_float(p0.y);
    acc.x += v0 * x0.x; acc.y += v0 * x0.y; acc.z += v0 * x0.z; acc.w += v0 * x0.w;
  }
#pragma unroll
  for (int d = 8; d < 64; d <<= 1) {
    acc.x += __shfl_xor(acc.x, d);
    acc.y += __shfl_xor(acc.y, d);
    acc.z += __shfl_xor(acc.z, d);
    acc.w += __shfl_xor(acc.w, d);
  }
  if (slot == 0) *(float4*)(Tx + (long)wid * 32 + f4 * 4) = acc;
}

// one wave per 2 nodes per iteration; lane = output k; fast exp/rcp math
__global__ void __launch_bounds__(T256, 3)
gate_kernel(const float* __restrict__ x, const float* __restrict__ Tx,
            const float* __restrict__ Wx0, const float* __restrict__ Wx1,
            const float* __restrict__ bx, const float* __restrict__ bh,
            const float* __restrict__ Wlin, const float* __restrict__ blin,
            float* __restrict__ out, int n) {
  int lane = threadIdx.x & 63;
  int wave = blockIdx.x * (T256 / 64) + (threadIdx.x >> 6);
  int nwaves = gridDim.x * (T256 / 64);

  float wz0[32], wz1[32], wt0[32], wt1[32];
#pragma unroll
  for (int f = 0; f < 32; f++) {
    wz0[f] = Wx0[f * 64 + lane];
    wz1[f] = Wx1[f * 64 + lane];
    wt0[f] = Wx0[4096 + f * 64 + lane];
    wt1[f] = Wx1[4096 + f * 64 + lane];
  }
  float bz = bx[lane] + bh[lane];
  float bt = bx[128 + lane] + bh[128 + lane];
  float wl = Wlin[lane];
  float bl = blin[0];

  for (int base = wave * 2; base < n; base += nwaves * 2) {
    int n1 = base + 1;
    bool has1 = n1 < n;
    const float4* xp0 = (const float4*)(x + (long)base * 32);
    const float4* tp0 = (const float4*)(Tx + (long)base * 32);
    float az0 = bz, at0 = bt, az1 = bz, at1 = bt;
#pragma unroll
    for (int c = 0; c < 8; c++) {
      float4 xa = xp0[c];
      float4 ta = tp0[c];
      az0 += xa.x * wz0[4 * c + 0] + xa.y * wz0[4 * c + 1] + xa.z * wz0[4 * c + 2] + xa.w * wz0[4 * c + 3];
      az0 += ta.x * wz1[4 * c + 0] + ta.y * wz1[4 * c + 1] + ta.z * wz1[4 * c + 2] + ta.w * wz1[4 * c + 3];
      at0 += xa.x * wt0[4 * c + 0] + xa.y * wt0[4 * c + 1] + xa.z * wt0[4 * c + 2] + xa.w * wt0[4 * c + 3];
      at0 += ta.x * wt1[4 * c + 0] + ta.y * wt1[4 * c + 1] + ta.z * wt1[4 * c + 2] + ta.w * wt1[4 * c + 3];
    }
    if (has1) {
      const float4* xp1 = xp0 + 8;
      const float4* tp1 = tp0 + 8;
#pragma unroll
      for (int c = 0; c < 8; c++) {
        float4 xa = xp1[c];
        float4 ta = tp1[c];
        az1 += xa.x * wz0[4 * c + 0] + xa.y * wz0[4 * c + 1] + xa.z * wz0[4 * c + 2] + xa.w * wz0[4 * c + 3];
        az1 += ta.x * wz1[4 * c + 0] + ta.y * wz1[4 * c + 1] + ta.z * wz1[4 * c + 2] + ta.w * wz1[4 * c + 3];
        at1 += xa.x * wt0[4 * c + 0] + xa.y * wt0[4 * c + 1] + xa.z * wt0[4 * c + 2] + xa.w * wt0[4 * c + 3];
        at1 += ta.x * wt1[4 * c + 0] + ta.y * wt1[4 * c + 1] + ta.z * wt1[4 * c + 2] + ta.w * wt1[4 * c + 3];
      }
    }
    // (1 - sigmoid(az)) = 1/(1+e^az);  tanh(at) = 1 - 2/(e^{2at}+1)
    float c0 = __builtin_amdgcn_rcpf(1.0f + __expf(az0)) *
               (1.0f - 2.0f * __builtin_amdgcn_rcpf(__expf(2.0f * at0) + 1.0f)) * wl;
    float c1 = __builtin_amdgcn_rcpf(1.0f + __expf(az1)) *
               (1.0f - 2.0f * __builtin_amdgcn_rcpf(__expf(2.0f * at1) + 1.0f)) * wl;
#pragma unroll
    for (int d = 1; d < 64; d <<= 1) {
      c0 += __shfl_xor(c0, d);
      c1 += __shfl_xor(c1, d);
    }
    if (lane == 0) {
      out[base] = c0 + bl;
      if (has1) out[n1] = c1 + bl;
    }
  }
}

extern "C" void kernel_launch(void* const* d_in, const int* in_sizes, int n_in,
                              void* d_out, int out_size, void* d_ws, size_t ws_size,
                              hipStream_t stream) {
  const float* x    = (const float*)d_in[0];
  const float* ew   = (const float*)d_in[1];
  const float* Wx0  = (const float*)d_in[2];
  const float* Wx1  = (const float*)d_in[3];
  const float* bx   = (const float*)d_in[4];
  const float* bh   = (const float*)d_in[7];
  const float* Wlin = (const float*)d_in[8];
  const float* blin = (const float*)d_in[9];
  const int*   ei   = (const int*)d_in[10];

  int N = in_sizes[0] / 32;
  int E = in_sizes[1];
  const int* row = ei;
  const int* col = ei + E;
  float* out = (float*)d_out;
  long tthreads = (long)N * 64;
  int nRB = (N + RANGE_B - 1) / RANGE_B;
  int nRD = (N + RANGE_D - 1) / RANGE_D;

  // layout: [Tx 32N][disq N][starts N][bsum 1024][H nB*N][degH∪pairs max(nB*N,2E)]
  // nB must keep chunk = ceil(E/nB) < 65536 for packed-u16 counting
  int nBopts[3] = {64, 48, 32};
  int nB = 0;
  size_t wTx = (size_t)N * 32, wRegion = 0;
  for (int k = 0; k < 3; k++) {
    size_t cb = (size_t)nBopts[k];
    if ((size_t)(E + nBopts[k] - 1) / nBopts[k] > 65535) continue;
    size_t h = cb * N;
    size_t region = h > (size_t)2 * E ? h : (size_t)2 * E;
    size_t tot = wTx + N + N + 1024 + h + region;
    if (tot * 4 <= ws_size) { nB = nBopts[k]; wRegion = region; break; }
  }

  if (nB > 0 && N <= 2 * HALF_N) {
    float* Tx     = (float*)d_ws;
    float* disq   = Tx + wTx;
    int*   starts = (int*)(disq + N);
    int*   bsum   = starts + N;
    int*   H      = bsum + 1024;
    float* degH   = (float*)(H + (size_t)nB * N);   // aliased with pairs (degH dead first)
    int2*  pairs  = (int2*)degH;

    int chunk = (E + nB - 1) / nB;
    int nb1 = (N + SB * ITEMS - 1) / (SB * ITEMS);

    histc_kernel<<<nB, BIG, 0, stream>>>(col, H, E, N, chunk);
    histd_kernel<<<dim3(nB, nRD), BIG, 0, stream>>>(row, ew, degH, E, N, chunk);
    colscan_kernel<<<(N + T256 - 1) / T256, T256, 0, stream>>>(H, degH, disq, starts, N, nB);
    scan1_kernel<<<nb1, SB, 0, stream>>>(starts, bsum, N);
    scan_top_kernel<<<1, SB, 0, stream>>>(bsum, nb1);
    scan_add_kernel<<<(N + T256 - 1) / T256, T256, 0, stream>>>(starts, bsum, N);
    bucket2_kernel<<<dim3(nB, nRB), BIG, 0, stream>>>(row, col, ew, disq, H, starts, pairs, E, N, chunk);
    gather_kernel<0><<<(int)((tthreads + T256 - 1) / T256), T256, 0, stream>>>(
        x, starts, pairs, Tx, N, E);
    gate_kernel<<<1024, T256, 0, stream>>>(x, Tx, Wx0, Wx1, bx, bh, Wlin, blin, out, N);
  } else {
    // legacy: device-scope atomics
    float* Tx     = (float*)d_ws;
    float* disq   = Tx + wTx;
    int*   starts = (int*)(disq + N);
    int*   bsum   = starts + N;
    int*   H      = bsum + 1024;                    // N counts
    float* degH   = (float*)(H + N);                // N deg
    size_t head = wTx + N + N + 1024 + N + N;
    if (head & 1) head++;
    int2* pairs = (int2*)((float*)d_ws + head);
    int nb1 = (N + SB * ITEMS - 1) / (SB * ITEMS);
    int eb = (E + T256 - 1) / T256;

    zero_kernel<<<256, T256, 0, stream>>>(H, N);
    zero_kernel<<<256, T256, 0, stream>>>((int*)degH, N);
    deghist_dev_kernel<<<eb, T256, 0, stream>>>(ew, row, col, degH, H, E);
    colscan_kernel<<<(N + T256 - 1) / T256, T256, 0, stream>>>(H, degH, disq, starts, N, 1);
    scan1_kernel<<<nb1, SB, 0, stream>>>(starts, bsum, N);
    scan_top_kernel<<<1, SB, 0, stream>>>(bsum, nb1);
    scan_add_kernel<<<(N + T256 - 1) / T256, T256, 0, stream>>>(starts, bsum, N);
    bucket_dev_kernel<<<eb, T256, 0, stream>>>(ew, row, col, disq, starts, pairs, E);
    gather_kernel<1><<<(int)((tthreads + T256 - 1) / T256), T256, 0, stream>>>(
        x, starts, pairs, Tx, N, E);
    gate_kernel<<<1024, T256, 0, stream>>>(x, Tx, Wx0, Wx1, bx, bh, Wlin, blin, out, N);
  }
}

// Round 10
// 194.777 us; speedup vs baseline: 1.6175x; 1.6175x over previous
//
#include <hip/hip_runtime.h>

#define T256 256
#define SB 1024
#define BIG 1024
#define RANGE_D 25000   // deg f32 bins/pass: 100 KB LDS, 2 passes
#define RANGE_B 25000   // bucket cursors/pass: 100 KB LDS, 2 passes
#define HALF_N 25000    // packed u16 count bins: (N+1)/2 u32 = 100 KB, 1 pass
#define ITEMS 8         // scan1: 8192 elements per block (bsum index = g>>13)

// ================= atomic-free path =================

// single pass: packed-u16 count histogram of col over ALL N bins (chunk <= 65535)
__global__ void __launch_bounds__(BIG)
histc_kernel(const int* __restrict__ col, int* __restrict__ H, int E, int N, int chunk) {
  __shared__ unsigned sc32[HALF_N];
  int b = blockIdx.x;
  long base = (long)b * chunk;
  int cnt = (int)min((long)chunk, (long)E - base);
  if (cnt < 0) cnt = 0;
  int t = threadIdx.x;
  int half = (N + 1) >> 1;
  for (int i = t; i < half; i += BIG) sc32[i] = 0u;
  __syncthreads();
  for (int i = t; i < cnt; i += BIG) {
    int c = col[base + i];
    atomicAdd(&sc32[c >> 1], 1u << ((c & 1) << 4));   // LDS atomic, packed u16
  }
  __syncthreads();
  for (int i = t; i < N; i += BIG)
    H[(long)b * N + i] = (int)((sc32[i >> 1] >> ((i & 1) << 4)) & 0xFFFFu);
}

// 2 range-passes: f32 weighted histogram of row
__global__ void __launch_bounds__(BIG)
histd_kernel(const int* __restrict__ row, const float* __restrict__ w,
             float* __restrict__ degH, int E, int N, int chunk) {
  __shared__ float sd[RANGE_D];
  int b = blockIdx.x;
  int lo = blockIdx.y * RANGE_D;
  int hi = min(lo + RANGE_D, N);
  int len = hi - lo;
  long base = (long)b * chunk;
  int cnt = (int)min((long)chunk, (long)E - base);
  if (cnt < 0) cnt = 0;
  int t = threadIdx.x;
  for (int i = t; i < len; i += BIG) sd[i] = 0.f;
  __syncthreads();
  for (int i = t; i < cnt; i += BIG) {
    long e = base + i;
    int r = row[e];
    if (r >= lo && r < hi) atomicAdd(&sd[r - lo], w[e]);   // LDS atomic
  }
  __syncthreads();
  for (int i = t; i < len; i += BIG) degH[(long)b * N + lo + i] = sd[i];
}

// thread-per-bin: exclusive column prefix of H over blocks (coalesced), totals -> cnt,
// fused degH column-reduce -> disq
__global__ void colscan_kernel(int* __restrict__ H, const float* __restrict__ degH,
                               float* __restrict__ disq, int* __restrict__ cnt,
                               int N, int nB) {
  int c = blockIdx.x * blockDim.x + threadIdx.x;
  if (c >= N) return;
  int s = 0;
  float d = 0.f;
  for (int b = 0; b < nB; b++) {
    long idx = (long)b * N + c;
    int h = H[idx];
    H[idx] = s;       // exclusive prefix within column
    s += h;
    d += degH[idx];
  }
  cnt[c] = s;
  disq[c] = (d > 0.f) ? rsqrtf(d) : 0.f;
}

// scan stage 1 over contiguous array (8192 elems/block)
__global__ void __launch_bounds__(SB)
scan1_kernel(int* __restrict__ a, int* __restrict__ bsum, int n) {
  __shared__ int s[SB];
  int t = threadIdx.x;
  int g0 = blockIdx.x * (SB * ITEMS) + t * ITEMS;
  int v[ITEMS];
  int tot = 0;
#pragma unroll
  for (int k = 0; k < ITEMS; k++) {
    int g = g0 + k;
    int u = (g < n) ? a[g] : 0;
    v[k] = u; tot += u;
  }
  s[t] = tot;
  __syncthreads();
  for (int d = 1; d < SB; d <<= 1) {
    int u = (t >= d) ? s[t - d] : 0;
    __syncthreads();
    s[t] += u;
    __syncthreads();
  }
  int run = s[t] - tot;
#pragma unroll
  for (int k = 0; k < ITEMS; k++) {
    int g = g0 + k;
    if (g < n) a[g] = run;
    run += v[k];
  }
  if (t == SB - 1) bsum[blockIdx.x] = s[SB - 1];
}

__global__ void __launch_bounds__(SB)
scan_top_kernel(int* __restrict__ bsum, int nb) {
  __shared__ int s[SB];
  int t = threadIdx.x;
  int v = (t < nb) ? bsum[t] : 0;
  s[t] = v;
  __syncthreads();
  for (int d = 1; d < SB; d <<= 1) {
    int u = (t >= d) ? s[t - d] : 0;
    __syncthreads();
    s[t] += u;
    __syncthreads();
  }
  if (t < nb) bsum[t] = s[t] - v;
}

__global__ void scan_add_kernel(int* __restrict__ a, const int* __restrict__ bsum, int n) {
  int g = blockIdx.x * blockDim.x + threadIdx.x;
  if (g < n) a[g] += bsum[g >> 13];
}

// grid (nB, nRB): block (b,p) places chunk b's edges with col in range p.
// cursor base = starts[c] + H[b][c]; LDS atomics only.
__global__ void __launch_bounds__(BIG)
bucket2_kernel(const int* __restrict__ row, const int* __restrict__ col,
               const float* __restrict__ w, const float* __restrict__ disq,
               const int* __restrict__ H, const int* __restrict__ starts,
               int2* __restrict__ pairs, int E, int N, int chunk) {
  __shared__ int cur[RANGE_B];
  int b = blockIdx.x;
  int lo = blockIdx.y * RANGE_B;
  int hi = min(lo + RANGE_B, N);
  int len = hi - lo;
  long base = (long)b * chunk;
  int cnt = (int)min((long)chunk, (long)E - base);
  if (cnt < 0) cnt = 0;
  int t = threadIdx.x;
  for (int i = t; i < len; i += BIG)
    cur[i] = H[(long)b * N + lo + i] + starts[lo + i];
  __syncthreads();
  for (int i = t; i < cnt; i += BIG) {
    long e = base + i;
    int c = col[e];
    if (c >= lo && c < hi) {
      int r = row[e];
      float nm = -w[e] * disq[r] * disq[c];
      int pos = atomicAdd(&cur[c - lo], 1);   // LDS atomic, exclusive (b,c) ranges
      pairs[pos] = make_int2(r, __float_as_int(nm));
    }
  }
}

// ================= legacy fallback (device atomics) =================

__global__ void zero_kernel(int* __restrict__ p, long n) {
  long i = (long)blockIdx.x * blockDim.x + threadIdx.x;
  long stride = (long)gridDim.x * blockDim.x;
  for (; i < n; i += stride) p[i] = 0;
}

__global__ void deghist_dev_kernel(const float* __restrict__ w, const int* __restrict__ row,
                                   const int* __restrict__ col, float* __restrict__ deg,
                                   int* __restrict__ cntArr, int E) {
  int e = blockIdx.x * blockDim.x + threadIdx.x;
  if (e < E) {
    atomicAdd(&deg[row[e]], w[e]);
    atomicAdd(&cntArr[col[e]], 1);
  }
}

__global__ void bucket_dev_kernel(const float* __restrict__ w, const int* __restrict__ row,
                                  const int* __restrict__ col, const float* __restrict__ disq,
                                  int* __restrict__ off, int2* __restrict__ pairs, int E) {
  int e = blockIdx.x * blockDim.x + threadIdx.x;
  if (e >= E) return;
  int r = row[e], c = col[e];
  float v = -w[e] * disq[r] * disq[c];
  int p = atomicAdd(&off[c], 1);
  pairs[p] = make_int2(r, __float_as_int(v));
}

// ================= shared tail =================

// MODE 0: S[c] = start, end = S[c+1] (or E).  MODE 1: S[c] = end, start = S[c-1] (or 0).
template <int MODE>
__global__ void gather_kernel(const float* __restrict__ x, const int* __restrict__ S,
                              const int2* __restrict__ pairs, float* __restrict__ Tx,
                              int n, int E) {
  int wid = (int)(((long)blockIdx.x * blockDim.x + threadIdx.x) >> 6);
  if (wid >= n) return;
  int lane = threadIdx.x & 63;
  int slot = lane >> 3;
  int f4 = lane & 7;
  int start, end;
  if (MODE == 0) { start = S[wid]; end = (wid + 1 < n) ? S[wid + 1] : E; }
  else           { start = wid ? S[wid - 1] : 0; end = S[wid]; }
  float4 acc = make_float4(0.f, 0.f, 0.f, 0.f);
  int i = start + slot;
  // 2-deep unroll: 16 edges in flight per wave
  for (; i + 8 < end; i += 16) {
    int2 p0 = pairs[i];
    int2 p1 = pairs[i + 8];
    float4 x0 = *(const float4*)(x + (long)p0.x * 32 + f4 * 4);
    float4 x1 = *(const float4*)(x + (long)p1.x * 32 + f4 * 4);
    float v0 = __int_as_float(p0.y);
    float v1 = __int_as_float(p1.y);
    acc.x += v0 * x0.x; acc.y += v0 * x0.y; acc.z += v0 * x0.z; acc.w += v0 * x0.w;
    acc.x += v1 * x1.x; acc.y += v1 * x1.y; acc.z += v1 * x1.z; acc.w += v1 * x1.w;
  }
  if (i < end) {
    int2 p0 = pairs[i];
    float4 x0 = *(const float4*)(x + (long)p0.x * 32 + f4 * 4);
    float v0 = __int_as_float(p0.y);
    acc.x += v0 * x0.x; acc.y += v0 * x0.y; acc.z += v0 * x0.z; acc.w += v0 * x0.w;
  }
#pragma unroll
  for (int d = 8; d < 64; d <<= 1) {
    acc.x += __shfl_xor(acc.x, d);
    acc.y += __shfl_xor(acc.y, d);
    acc.z += __shfl_xor(acc.z, d);
    acc.w += __shfl_xor(acc.w, d);
  }
  if (slot == 0) *(float4*)(Tx + (long)wid * 32 + f4 * 4) = acc;
}

// one wave per node; lane = output k; weights register-resident (needs >=128 VGPR:
// launch_bounds(256,2) -> ~116 VGPR alloc observed, NO spill. Do NOT raise to 3:
// round-9 showed (256,3) caps at 84 VGPR and spills the weight arrays (318MB FETCH).
__global__ void __launch_bounds__(T256, 2)
gate_kernel(const float* __restrict__ x, const float* __restrict__ Tx,
            const float* __restrict__ Wx0, const float* __restrict__ Wx1,
            const float* __restrict__ bx, const float* __restrict__ bh,
            const float* __restrict__ Wlin, const float* __restrict__ blin,
            float* __restrict__ out, int n) {
  int lane = threadIdx.x & 63;
  int wave = blockIdx.x * (T256 / 64) + (threadIdx.x >> 6);
  int nwaves = gridDim.x * (T256 / 64);

  float wz0[32], wz1[32], wt0[32], wt1[32];
#pragma unroll
  for (int f = 0; f < 32; f++) {
    wz0[f] = Wx0[f * 64 + lane];
    wz1[f] = Wx1[f * 64 + lane];
    wt0[f] = Wx0[4096 + f * 64 + lane];
    wt1[f] = Wx1[4096 + f * 64 + lane];
  }
  float bz = bx[lane] + bh[lane];
  float bt = bx[128 + lane] + bh[128 + lane];
  float wl = Wlin[lane];
  float bl = blin[0];

  for (int node = wave; node < n; node += nwaves) {
    const float4* xp = (const float4*)(x + (long)node * 32);
    const float4* tp = (const float4*)(Tx + (long)node * 32);
    float azx = 0.f, azt = 0.f, atx = 0.f, att = 0.f;
#pragma unroll
    for (int c = 0; c < 8; c++) {
      float4 xa = xp[c];
      float4 ta = tp[c];
      azx += xa.x * wz0[4 * c + 0] + xa.y * wz0[4 * c + 1] + xa.z * wz0[4 * c + 2] + xa.w * wz0[4 * c + 3];
      azt += ta.x * wz1[4 * c + 0] + ta.y * wz1[4 * c + 1] + ta.z * wz1[4 * c + 2] + ta.w * wz1[4 * c + 3];
      atx += xa.x * wt0[4 * c + 0] + xa.y * wt0[4 * c + 1] + xa.z * wt0[4 * c + 2] + xa.w * wt0[4 * c + 3];
      att += ta.x * wt1[4 * c + 0] + ta.y * wt1[4 * c + 1] + ta.z * wt1[4 * c + 2] + ta.w * wt1[4 * c + 3];
    }
    float az = azx + azt + bz;
    float at = atx + att + bt;
    // (1 - sigmoid(az)) = 1/(1+e^az);  tanh(at) = 1 - 2/(e^{2at}+1)
    float contrib = __builtin_amdgcn_rcpf(1.0f + __expf(az)) *
                    (1.0f - 2.0f * __builtin_amdgcn_rcpf(__expf(2.0f * at) + 1.0f)) * wl;
#pragma unroll
    for (int d = 1; d < 64; d <<= 1) contrib += __shfl_xor(contrib, d);
    if (lane == 0) out[node] = contrib + bl;
  }
}

extern "C" void kernel_launch(void* const* d_in, const int* in_sizes, int n_in,
                              void* d_out, int out_size, void* d_ws, size_t ws_size,
                              hipStream_t stream) {
  const float* x    = (const float*)d_in[0];
  const float* ew   = (const float*)d_in[1];
  const float* Wx0  = (const float*)d_in[2];
  const float* Wx1  = (const float*)d_in[3];
  const float* bx   = (const float*)d_in[4];
  const float* bh   = (const float*)d_in[7];
  const float* Wlin = (const float*)d_in[8];
  const float* blin = (const float*)d_in[9];
  const int*   ei   = (const int*)d_in[10];

  int N = in_sizes[0] / 32;
  int E = in_sizes[1];
  const int* row = ei;
  const int* col = ei + E;
  float* out = (float*)d_out;
  long tthreads = (long)N * 64;
  int nRB = (N + RANGE_B - 1) / RANGE_B;
  int nRD = (N + RANGE_D - 1) / RANGE_D;

  // layout: [Tx 32N][disq N][starts N][bsum 1024][H nB*N][degH∪pairs max(nB*N,2E)]
  // nB must keep chunk = ceil(E/nB) < 65536 for packed-u16 counting
  int nBopts[3] = {64, 48, 32};
  int nB = 0;
  size_t wTx = (size_t)N * 32, wRegion = 0;
  for (int k = 0; k < 3; k++) {
    size_t cb = (size_t)nBopts[k];
    if ((size_t)(E + nBopts[k] - 1) / nBopts[k] > 65535) continue;
    size_t h = cb * N;
    size_t region = h > (size_t)2 * E ? h : (size_t)2 * E;
    size_t tot = wTx + N + N + 1024 + h + region;
    if (tot * 4 <= ws_size) { nB = nBopts[k]; wRegion = region; break; }
  }

  if (nB > 0 && N <= 2 * HALF_N) {
    float* Tx     = (float*)d_ws;
    float* disq   = Tx + wTx;
    int*   starts = (int*)(disq + N);
    int*   bsum   = starts + N;
    int*   H      = bsum + 1024;
    float* degH   = (float*)(H + (size_t)nB * N);   // aliased with pairs (degH dead first)
    int2*  pairs  = (int2*)degH;

    int chunk = (E + nB - 1) / nB;
    int nb1 = (N + SB * ITEMS - 1) / (SB * ITEMS);

    histc_kernel<<<nB, BIG, 0, stream>>>(col, H, E, N, chunk);
    histd_kernel<<<dim3(nB, nRD), BIG, 0, stream>>>(row, ew, degH, E, N, chunk);
    colscan_kernel<<<(N + T256 - 1) / T256, T256, 0, stream>>>(H, degH, disq, starts, N, nB);
    scan1_kernel<<<nb1, SB, 0, stream>>>(starts, bsum, N);
    scan_top_kernel<<<1, SB, 0, stream>>>(bsum, nb1);
    scan_add_kernel<<<(N + T256 - 1) / T256, T256, 0, stream>>>(starts, bsum, N);
    bucket2_kernel<<<dim3(nB, nRB), BIG, 0, stream>>>(row, col, ew, disq, H, starts, pairs, E, N, chunk);
    gather_kernel<0><<<(int)((tthreads + T256 - 1) / T256), T256, 0, stream>>>(
        x, starts, pairs, Tx, N, E);
    gate_kernel<<<1024, T256, 0, stream>>>(x, Tx, Wx0, Wx1, bx, bh, Wlin, blin, out, N);
  } else {
    // legacy: device-scope atomics
    float* Tx     = (float*)d_ws;
    float* disq   = Tx + wTx;
    int*   starts = (int*)(disq + N);
    int*   bsum   = starts + N;
    int*   H      = bsum + 1024;                    // N counts
    float* degH   = (float*)(H + N);                // N deg
    size_t head = wTx + N + N + 1024 + N + N;
    if (head & 1) head++;
    int2* pairs = (int2*)((float*)d_ws + head);
    int nb1 = (N + SB * ITEMS - 1) / (SB * ITEMS);
    int eb = (E + T256 - 1) / T256;

    zero_kernel<<<256, T256, 0, stream>>>(H, N);
    zero_kernel<<<256, T256, 0, stream>>>((int*)degH, N);
    deghist_dev_kernel<<<eb, T256, 0, stream>>>(ew, row, col, degH, H, E);
    colscan_kernel<<<(N + T256 - 1) / T256, T256, 0, stream>>>(H, degH, disq, starts, N, 1);
    scan1_kernel<<<nb1, SB, 0, stream>>>(starts, bsum, N);
    scan_top_kernel<<<1, SB, 0, stream>>>(bsum, nb1);
    scan_add_kernel<<<(N + T256 - 1) / T256, T256, 0, stream>>>(starts, bsum, N);
    bucket_dev_kernel<<<eb, T256, 0, stream>>>(ew, row, col, disq, starts, pairs, E);
    gather_kernel<1><<<(int)((tthreads + T256 - 1) / T256), T256, 0, stream>>>(
        x, starts, pairs, Tx, N, E);
    gate_kernel<<<1024, T256, 0, stream>>>(x, Tx, Wx0, Wx1, bx, bh, Wlin, blin, out, N);
  }
}

// Round 11
// 192.446 us; speedup vs baseline: 1.6371x; 1.0121x over previous
//
#include <hip/hip_runtime.h>

#define T256 256
#define SB 1024
#define BIG 1024
#define RANGE_D 25000   // deg f32 bins/pass: 100 KB LDS, 2 passes
#define RANGE_B 25000   // bucket cursors/pass: 100 KB LDS, 2 passes
#define HALF_N 25000    // packed u16 count bins: (N+1)/2 u32 = 100 KB, 1 pass
#define ITEMS 8         // scan1: 8192 elements per block (bsum index = g>>13)

// ================= atomic-free path =================

// single pass: packed-u16 count histogram of col over ALL N bins (chunk <= 65535)
__global__ void __launch_bounds__(BIG)
histc_kernel(const int* __restrict__ col, int* __restrict__ H, int E, int N, int chunk) {
  __shared__ unsigned sc32[HALF_N];
  int b = blockIdx.x;
  long base = (long)b * chunk;
  int cnt = (int)min((long)chunk, (long)E - base);
  if (cnt < 0) cnt = 0;
  int t = threadIdx.x;
  int half = (N + 1) >> 1;
  for (int i = t; i < half; i += BIG) sc32[i] = 0u;
  __syncthreads();
  for (int i = t; i < cnt; i += BIG) {
    int c = col[base + i];
    atomicAdd(&sc32[c >> 1], 1u << ((c & 1) << 4));   // LDS atomic, packed u16
  }
  __syncthreads();
  for (int i = t; i < N; i += BIG)
    H[(long)b * N + i] = (int)((sc32[i >> 1] >> ((i & 1) << 4)) & 0xFFFFu);
}

// 2 range-passes: f32 weighted histogram of row
__global__ void __launch_bounds__(BIG)
histd_kernel(const int* __restrict__ row, const float* __restrict__ w,
             float* __restrict__ degH, int E, int N, int chunk) {
  __shared__ float sd[RANGE_D];
  int b = blockIdx.x;
  int lo = blockIdx.y * RANGE_D;
  int hi = min(lo + RANGE_D, N);
  int len = hi - lo;
  long base = (long)b * chunk;
  int cnt = (int)min((long)chunk, (long)E - base);
  if (cnt < 0) cnt = 0;
  int t = threadIdx.x;
  for (int i = t; i < len; i += BIG) sd[i] = 0.f;
  __syncthreads();
  for (int i = t; i < cnt; i += BIG) {
    long e = base + i;
    int r = row[e];
    if (r >= lo && r < hi) atomicAdd(&sd[r - lo], w[e]);   // LDS atomic
  }
  __syncthreads();
  for (int i = t; i < len; i += BIG) degH[(long)b * N + lo + i] = sd[i];
}

// thread-per-bin: exclusive column prefix of H over blocks (coalesced), totals -> cnt,
// fused degH column-reduce -> disq
__global__ void colscan_kernel(int* __restrict__ H, const float* __restrict__ degH,
                               float* __restrict__ disq, int* __restrict__ cnt,
                               int N, int nB) {
  int c = blockIdx.x * blockDim.x + threadIdx.x;
  if (c >= N) return;
  int s = 0;
  float d = 0.f;
  for (int b = 0; b < nB; b++) {
    long idx = (long)b * N + c;
    int h = H[idx];
    H[idx] = s;       // exclusive prefix within column
    s += h;
    d += degH[idx];
  }
  cnt[c] = s;
  disq[c] = (d > 0.f) ? rsqrtf(d) : 0.f;
}

// scan stage 1 over contiguous array (8192 elems/block)
__global__ void __launch_bounds__(SB)
scan1_kernel(int* __restrict__ a, int* __restrict__ bsum, int n) {
  __shared__ int s[SB];
  int t = threadIdx.x;
  int g0 = blockIdx.x * (SB * ITEMS) + t * ITEMS;
  int v[ITEMS];
  int tot = 0;
#pragma unroll
  for (int k = 0; k < ITEMS; k++) {
    int g = g0 + k;
    int u = (g < n) ? a[g] : 0;
    v[k] = u; tot += u;
  }
  s[t] = tot;
  __syncthreads();
  for (int d = 1; d < SB; d <<= 1) {
    int u = (t >= d) ? s[t - d] : 0;
    __syncthreads();
    s[t] += u;
    __syncthreads();
  }
  int run = s[t] - tot;
#pragma unroll
  for (int k = 0; k < ITEMS; k++) {
    int g = g0 + k;
    if (g < n) a[g] = run;
    run += v[k];
  }
  if (t == SB - 1) bsum[blockIdx.x] = s[SB - 1];
}

__global__ void __launch_bounds__(SB)
scan_top_kernel(int* __restrict__ bsum, int nb) {
  __shared__ int s[SB];
  int t = threadIdx.x;
  int v = (t < nb) ? bsum[t] : 0;
  s[t] = v;
  __syncthreads();
  for (int d = 1; d < SB; d <<= 1) {
    int u = (t >= d) ? s[t - d] : 0;
    __syncthreads();
    s[t] += u;
    __syncthreads();
  }
  if (t < nb) bsum[t] = s[t] - v;
}

__global__ void scan_add_kernel(int* __restrict__ a, const int* __restrict__ bsum, int n) {
  int g = blockIdx.x * blockDim.x + threadIdx.x;
  if (g < n) a[g] += bsum[g >> 13];
}

// grid (nB, nRB): block (b,p) places chunk b's edges with col in range p.
// cursor base = starts[c] + H[b][c]; LDS atomics only.
__global__ void __launch_bounds__(BIG)
bucket2_kernel(const int* __restrict__ row, const int* __restrict__ col,
               const float* __restrict__ w, const float* __restrict__ disq,
               const int* __restrict__ H, const int* __restrict__ starts,
               int2* __restrict__ pairs, int E, int N, int chunk) {
  __shared__ int cur[RANGE_B];
  int b = blockIdx.x;
  int lo = blockIdx.y * RANGE_B;
  int hi = min(lo + RANGE_B, N);
  int len = hi - lo;
  long base = (long)b * chunk;
  int cnt = (int)min((long)chunk, (long)E - base);
  if (cnt < 0) cnt = 0;
  int t = threadIdx.x;
  for (int i = t; i < len; i += BIG)
    cur[i] = H[(long)b * N + lo + i] + starts[lo + i];
  __syncthreads();
  for (int i = t; i < cnt; i += BIG) {
    long e = base + i;
    int c = col[e];
    if (c >= lo && c < hi) {
      int r = row[e];
      float nm = -w[e] * disq[r] * disq[c];
      int pos = atomicAdd(&cur[c - lo], 1);   // LDS atomic, exclusive (b,c) ranges
      pairs[pos] = make_int2(r, __float_as_int(nm));
    }
  }
}

// ================= legacy fallback (device atomics) =================

__global__ void zero_kernel(int* __restrict__ p, long n) {
  long i = (long)blockIdx.x * blockDim.x + threadIdx.x;
  long stride = (long)gridDim.x * blockDim.x;
  for (; i < n; i += stride) p[i] = 0;
}

__global__ void deghist_dev_kernel(const float* __restrict__ w, const int* __restrict__ row,
                                   const int* __restrict__ col, float* __restrict__ deg,
                                   int* __restrict__ cntArr, int E) {
  int e = blockIdx.x * blockDim.x + threadIdx.x;
  if (e < E) {
    atomicAdd(&deg[row[e]], w[e]);
    atomicAdd(&cntArr[col[e]], 1);
  }
}

__global__ void bucket_dev_kernel(const float* __restrict__ w, const int* __restrict__ row,
                                  const int* __restrict__ col, const float* __restrict__ disq,
                                  int* __restrict__ off, int2* __restrict__ pairs, int E) {
  int e = blockIdx.x * blockDim.x + threadIdx.x;
  if (e >= E) return;
  int r = row[e], c = col[e];
  float v = -w[e] * disq[r] * disq[c];
  int p = atomicAdd(&off[c], 1);
  pairs[p] = make_int2(r, __float_as_int(v));
}

// ================= shared tail =================

// MODE 0: S[c] = start, end = S[c+1] (or E).  MODE 1: S[c] = end, start = S[c-1] (or 0).
template <int MODE>
__global__ void gather_kernel(const float* __restrict__ x, const int* __restrict__ S,
                              const int2* __restrict__ pairs, float* __restrict__ Tx,
                              int n, int E) {
  int wid = (int)(((long)blockIdx.x * blockDim.x + threadIdx.x) >> 6);
  if (wid >= n) return;
  int lane = threadIdx.x & 63;
  int slot = lane >> 3;
  int f4 = lane & 7;
  int start, end;
  if (MODE == 0) { start = S[wid]; end = (wid + 1 < n) ? S[wid + 1] : E; }
  else           { start = wid ? S[wid - 1] : 0; end = S[wid]; }
  float4 acc = make_float4(0.f, 0.f, 0.f, 0.f);
  int i = start + slot;
  // 2-deep unroll: 16 edges in flight per wave
  for (; i + 8 < end; i += 16) {
    int2 p0 = pairs[i];
    int2 p1 = pairs[i + 8];
    float4 x0 = *(const float4*)(x + (long)p0.x * 32 + f4 * 4);
    float4 x1 = *(const float4*)(x + (long)p1.x * 32 + f4 * 4);
    float v0 = __int_as_float(p0.y);
    float v1 = __int_as_float(p1.y);
    acc.x += v0 * x0.x; acc.y += v0 * x0.y; acc.z += v0 * x0.z; acc.w += v0 * x0.w;
    acc.x += v1 * x1.x; acc.y += v1 * x1.y; acc.z += v1 * x1.z; acc.w += v1 * x1.w;
  }
  if (i < end) {
    int2 p0 = pairs[i];
    float4 x0 = *(const float4*)(x + (long)p0.x * 32 + f4 * 4);
    float v0 = __int_as_float(p0.y);
    acc.x += v0 * x0.x; acc.y += v0 * x0.y; acc.z += v0 * x0.z; acc.w += v0 * x0.w;
  }
#pragma unroll
  for (int d = 8; d < 64; d <<= 1) {
    acc.x += __shfl_xor(acc.x, d);
    acc.y += __shfl_xor(acc.y, d);
    acc.z += __shfl_xor(acc.z, d);
    acc.w += __shfl_xor(acc.w, d);
  }
  if (slot == 0) *(float4*)(Tx + (long)wid * 32 + f4 * 4) = acc;
}

// one wave per node; lane = output k. The 128 weight values are PINNED into VGPRs
// via an opaque asm def: round-10 showed the allocator otherwise remats the weight
// loads inside the node loop (VGPR_Count 84 < 128 -> 55.7us). launch_bounds(.,1)
// lifts the VGPR cap (round-9: (.,3) capped at 84 and spilled -> 318MB FETCH).
__global__ void __launch_bounds__(T256, 1)
gate_kernel(const float* __restrict__ x, const float* __restrict__ Tx,
            const float* __restrict__ Wx0, const float* __restrict__ Wx1,
            const float* __restrict__ bx, const float* __restrict__ bh,
            const float* __restrict__ Wlin, const float* __restrict__ blin,
            float* __restrict__ out, int n) {
  int lane = threadIdx.x & 63;
  int wave = blockIdx.x * (T256 / 64) + (threadIdx.x >> 6);
  int nwaves = gridDim.x * (T256 / 64);

  float wz0[32], wz1[32], wt0[32], wt1[32];
#pragma unroll
  for (int f = 0; f < 32; f++) {
    wz0[f] = Wx0[f * 64 + lane];
    wz1[f] = Wx1[f * 64 + lane];
    wt0[f] = Wx0[4096 + f * 64 + lane];
    wt1[f] = Wx1[4096 + f * 64 + lane];
  }
  // pin weights in registers: opaque defs the compiler cannot rematerialize through
#pragma unroll
  for (int f = 0; f < 32; f++) {
    asm volatile("" : "+v"(wz0[f]), "+v"(wz1[f]), "+v"(wt0[f]), "+v"(wt1[f]));
  }
  float bz = bx[lane] + bh[lane];
  float bt = bx[128 + lane] + bh[128 + lane];
  float wl = Wlin[lane];
  float bl = blin[0];

  for (int node = wave; node < n; node += nwaves) {
    const float4* xp = (const float4*)(x + (long)node * 32);
    const float4* tp = (const float4*)(Tx + (long)node * 32);
    float azx = 0.f, azt = 0.f, atx = 0.f, att = 0.f;
#pragma unroll
    for (int c = 0; c < 8; c++) {
      float4 xa = xp[c];
      float4 ta = tp[c];
      azx += xa.x * wz0[4 * c + 0] + xa.y * wz0[4 * c + 1] + xa.z * wz0[4 * c + 2] + xa.w * wz0[4 * c + 3];
      azt += ta.x * wz1[4 * c + 0] + ta.y * wz1[4 * c + 1] + ta.z * wz1[4 * c + 2] + ta.w * wz1[4 * c + 3];
      atx += xa.x * wt0[4 * c + 0] + xa.y * wt0[4 * c + 1] + xa.z * wt0[4 * c + 2] + xa.w * wt0[4 * c + 3];
      att += ta.x * wt1[4 * c + 0] + ta.y * wt1[4 * c + 1] + ta.z * wt1[4 * c + 2] + ta.w * wt1[4 * c + 3];
    }
    float az = azx + azt + bz;
    float at = atx + att + bt;
    // (1 - sigmoid(az)) = 1/(1+e^az);  tanh(at) = 1 - 2/(e^{2at}+1)
    float contrib = __builtin_amdgcn_rcpf(1.0f + __expf(az)) *
                    (1.0f - 2.0f * __builtin_amdgcn_rcpf(__expf(2.0f * at) + 1.0f)) * wl;
#pragma unroll
    for (int d = 1; d < 64; d <<= 1) contrib += __shfl_xor(contrib, d);
    if (lane == 0) out[node] = contrib + bl;
  }
}

extern "C" void kernel_launch(void* const* d_in, const int* in_sizes, int n_in,
                              void* d_out, int out_size, void* d_ws, size_t ws_size,
                              hipStream_t stream) {
  const float* x    = (const float*)d_in[0];
  const float* ew   = (const float*)d_in[1];
  const float* Wx0  = (const float*)d_in[2];
  const float* Wx1  = (const float*)d_in[3];
  const float* bx   = (const float*)d_in[4];
  const float* bh   = (const float*)d_in[7];
  const float* Wlin = (const float*)d_in[8];
  const float* blin = (const float*)d_in[9];
  const int*   ei   = (const int*)d_in[10];

  int N = in_sizes[0] / 32;
  int E = in_sizes[1];
  const int* row = ei;
  const int* col = ei + E;
  float* out = (float*)d_out;
  long tthreads = (long)N * 64;
  int nRB = (N + RANGE_B - 1) / RANGE_B;
  int nRD = (N + RANGE_D - 1) / RANGE_D;

  // layout: [Tx 32N][disq N][starts N][bsum 1024][H nB*N][degH∪pairs max(nB*N,2E)]
  // nB must keep chunk = ceil(E/nB) < 65536 for packed-u16 counting
  int nBopts[3] = {64, 48, 32};
  int nB = 0;
  size_t wTx = (size_t)N * 32, wRegion = 0;
  for (int k = 0; k < 3; k++) {
    size_t cb = (size_t)nBopts[k];
    if ((size_t)(E + nBopts[k] - 1) / nBopts[k] > 65535) continue;
    size_t h = cb * N;
    size_t region = h > (size_t)2 * E ? h : (size_t)2 * E;
    size_t tot = wTx + N + N + 1024 + h + region;
    if (tot * 4 <= ws_size) { nB = nBopts[k]; wRegion = region; break; }
  }

  if (nB > 0 && N <= 2 * HALF_N) {
    float* Tx     = (float*)d_ws;
    float* disq   = Tx + wTx;
    int*   starts = (int*)(disq + N);
    int*   bsum   = starts + N;
    int*   H      = bsum + 1024;
    float* degH   = (float*)(H + (size_t)nB * N);   // aliased with pairs (degH dead first)
    int2*  pairs  = (int2*)degH;

    int chunk = (E + nB - 1) / nB;
    int nb1 = (N + SB * ITEMS - 1) / (SB * ITEMS);

    histc_kernel<<<nB, BIG, 0, stream>>>(col, H, E, N, chunk);
    histd_kernel<<<dim3(nB, nRD), BIG, 0, stream>>>(row, ew, degH, E, N, chunk);
    colscan_kernel<<<(N + T256 - 1) / T256, T256, 0, stream>>>(H, degH, disq, starts, N, nB);
    scan1_kernel<<<nb1, SB, 0, stream>>>(starts, bsum, N);
    scan_top_kernel<<<1, SB, 0, stream>>>(bsum, nb1);
    scan_add_kernel<<<(N + T256 - 1) / T256, T256, 0, stream>>>(starts, bsum, N);
    bucket2_kernel<<<dim3(nB, nRB), BIG, 0, stream>>>(row, col, ew, disq, H, starts, pairs, E, N, chunk);
    gather_kernel<0><<<(int)((tthreads + T256 - 1) / T256), T256, 0, stream>>>(
        x, starts, pairs, Tx, N, E);
    gate_kernel<<<1024, T256, 0, stream>>>(x, Tx, Wx0, Wx1, bx, bh, Wlin, blin, out, N);
  } else {
    // legacy: device-scope atomics
    float* Tx     = (float*)d_ws;
    float* disq   = Tx + wTx;
    int*   starts = (int*)(disq + N);
    int*   bsum   = starts + N;
    int*   H      = bsum + 1024;                    // N counts
    float* degH   = (float*)(H + N);                // N deg
    size_t head = wTx + N + N + 1024 + N + N;
    if (head & 1) head++;
    int2* pairs = (int2*)((float*)d_ws + head);
    int nb1 = (N + SB * ITEMS - 1) / (SB * ITEMS);
    int eb = (E + T256 - 1) / T256;

    zero_kernel<<<256, T256, 0, stream>>>(H, N);
    zero_kernel<<<256, T256, 0, stream>>>((int*)degH, N);
    deghist_dev_kernel<<<eb, T256, 0, stream>>>(ew, row, col, degH, H, E);
    colscan_kernel<<<(N + T256 - 1) / T256, T256, 0, stream>>>(H, degH, disq, starts, N, 1);
    scan1_kernel<<<nb1, SB, 0, stream>>>(starts, bsum, N);
    scan_top_kernel<<<1, SB, 0, stream>>>(bsum, nb1);
    scan_add_kernel<<<(N + T256 - 1) / T256, T256, 0, stream>>>(starts, bsum, N);
    bucket_dev_kernel<<<eb, T256, 0, stream>>>(ew, row, col, disq, starts, pairs, E);
    gather_kernel<1><<<(int)((tthreads + T256 - 1) / T256), T256, 0, stream>>>(
        x, starts, pairs, Tx, N, E);
    gate_kernel<<<1024, T256, 0, stream>>>(x, Tx, Wx0, Wx1, bx, bh, Wlin, blin, out, N);
  }
}